// Round 12
// baseline (210.758 us; speedup 1.0000x reference)
//
#include <hip/hip_runtime.h>
#include <hip/hip_bf16.h>

#define N_NODES 100000
#define N_EDGES 3200000
#define IN_CH   128
#define HID     32
#define NB      1024             // dst buckets
#define NPB     98               // nodes per bucket (1024*98 = 100352 >= 100000)
#define CAP     4096             // per-bucket capacity (mean 3125, sigma 56, +17 sigma)
#define CHUNK   8192             // edges per block in scatter7
#define EPT     16               // edges per thread (CHUNK/512)
#define ACC_LD  33               // padded acc row stride
#define OCTN    12500u           // nodes per octant (finalize sort key)
#define FXS     1048576.0f       // 2^20 fixed-point scale
#define FXI     (1.0f/1048576.0f)
#define NTILE   6250             // 16-node MFMA tiles (100000/16 exact)
#define TPW     2                // tiles per wave in gemm1

// --- bf16 helpers ----------------------------------------------------------
__device__ __forceinline__ unsigned int pack_bf16x2(float a, float b) {
    unsigned int ua = __float_as_uint(a);
    unsigned int ub = __float_as_uint(b);
    ua = (ua + 0x7FFFu + ((ua >> 16) & 1u)) >> 16;
    ub = (ub + 0x7FFFu + ((ub >> 16) & 1u)) >> 16;
    return (ua & 0xFFFFu) | (ub << 16);
}
__device__ __forceinline__ float bf_lo(unsigned int v) { return __uint_as_float(v << 16); }
__device__ __forceinline__ float bf_hi(unsigned int v) { return __uint_as_float(v & 0xFFFF0000u); }
__device__ __forceinline__ int   f2fx(float f)         { return (int)(f * FXS); }
// truncate-to-bf16 as float (zero low mantissa bits)
__device__ __forceinline__ float hif(float f) {
    return __uint_as_float(__float_as_uint(f) & 0xFFFF0000u);
}
// pack two floats' TOP 16 bits (truncation) into one u32 (lo=a, hi=b)
__device__ __forceinline__ unsigned int tpack(float a, float b) {
    return (__float_as_uint(a) >> 16) | (__float_as_uint(b) & 0xFFFF0000u);
}
__device__ __forceinline__ unsigned short bf16_rne(float f) {
    unsigned int u = __float_as_uint(f);
    return (unsigned short)((u + 0x7FFFu + ((u >> 16) & 1u)) >> 16);
}

typedef short bf16x8 __attribute__((ext_vector_type(8)));
typedef float f32x4  __attribute__((ext_vector_type(4)));
union frag_u { bf16x8 f; unsigned int u[4]; };

// ---------------------------------------------------------------------------
// Detect int64 vs int32 edge_index; init bcur cursors. One block.
// ---------------------------------------------------------------------------
__global__ __launch_bounds__(256) void detect_init(const int* __restrict__ ei,
                                                   int* __restrict__ flag,
                                                   int* __restrict__ bcur) {
    __shared__ int nz;
    for (int j = threadIdx.x; j < NB; j += 256) bcur[j] = j * CAP;
    if (threadIdx.x == 0) nz = 0;
    __syncthreads();
    if (ei[2 * threadIdx.x + 1] != 0) atomicAdd(&nz, 1);
    __syncthreads();
    if (threadIdx.x == 0) flag[0] = (nz == 0) ? 1 : 0;
}

__device__ __forceinline__ int edge_at(const int* __restrict__ ei, int idx64,
                                       size_t pos) {
    if (idx64) return (int)((const long long*)ei)[pos];
    return ei[pos];
}

// ---------------------------------------------------------------------------
// Scatter edges into fixed-capacity dst-bucket regions of ebuf, 4 B packed
// (s<<8)|dloc. Register-staged single global read; LDS bucket sort; LINEAR
// flush (contiguous per-bucket runs, wave-coalesced). Reservation loop is
// ROTATED per block so co-resident blocks' global atomics decorrelate.
// ---------------------------------------------------------------------------
__global__ __launch_bounds__(512) void scatter7(
    const int* __restrict__ ei,
    const int* __restrict__ flag,
    int* __restrict__ bcur,
    unsigned int* __restrict__ ebuf) {
    __shared__ int cnt[NB];               // 4 KB  histogram, then cursor
    __shared__ int loff[NB];              // 4 KB  local exclusive offsets
    __shared__ int dlt[NB];               // 4 KB  global_base - loff
    __shared__ int tmp[512];              // 2 KB  scan temp
    __shared__ unsigned int   sbuf[CHUNK];// 32 KB sorted edges
    __shared__ unsigned short sbb[CHUNK]; // 16 KB bucket id per sorted slot

    int t = threadIdx.x;
    for (int j = t; j < NB; j += 512) cnt[j] = 0;
    __syncthreads();

    int e0 = blockIdx.x * CHUNK;
    int nE = N_EDGES - e0; if (nE > CHUNK) nE = CHUNK;
    int idx64 = flag[0];

    // single global read: stage this thread's <=16 edges in registers
    unsigned int rs[EPT], rd[EPT];
#pragma unroll
    for (int j = 0; j < EPT; ++j) {
        int i = t + j * 512;
        if (i < nE) {
            rs[j] = (unsigned int)edge_at(ei, idx64, (size_t)(e0 + i));
            rd[j] = (unsigned int)edge_at(ei, idx64, (size_t)N_EDGES + e0 + i);
        }
    }

    // dst histogram from registers (LDS atomics, native int)
#pragma unroll
    for (int j = 0; j < EPT; ++j) {
        int i = t + j * 512;
        if (i < nE) atomicAdd(&cnt[rd[j] / NPB], 1);
    }
    __syncthreads();

    // exclusive scan of cnt[1024]: thread t owns bins 2t, 2t+1
    int c0 = cnt[2 * t], c1 = cnt[2 * t + 1];
    int s = c0 + c1;
    tmp[t] = s;
    __syncthreads();
    for (int off = 1; off < 512; off <<= 1) {
        int x = 0;
        if (t >= off) x = tmp[t - off];
        __syncthreads();
        if (t >= off) tmp[t] += x;
        __syncthreads();
    }
    int base = tmp[t] - s;                // exclusive over thread groups
    loff[2 * t]     = base;
    loff[2 * t + 1] = base + c0;
    __syncthreads();

    // staggered reservation: rotate per block to decorrelate atomic bursts
    int rot = (blockIdx.x * 211) & (NB - 1);
    for (int jj = t; jj < NB; jj += 512) {
        int j = (jj + rot) & (NB - 1);
        int c = cnt[j];
        int gb = (c > 0) ? atomicAdd(&bcur[j], c) : 0;
        dlt[j] = gb - loff[j];
        cnt[j] = 0;                       // reuse as scatter cursor
    }
    __syncthreads();

    // LDS bucket-sort from registers
#pragma unroll
    for (int j = 0; j < EPT; ++j) {
        int i = t + j * 512;
        if (i < nE) {
            unsigned int b = rd[j] / NPB; // compile-time const -> magic mul
            int pos = loff[b] + atomicAdd(&cnt[b], 1);
            sbuf[pos] = (rs[j] << 8) | (rd[j] - b * NPB);
            sbb[pos]  = (unsigned short)b;
        }
    }
    __syncthreads();

    // linear flush -> contiguous per-bucket runs, wave-coalesced
    for (int i = t; i < nE; i += 512)
        ebuf[dlt[sbb[i]] + i] = sbuf[i];
}

// ---------------------------------------------------------------------------
// Per-bucket finalize: dst histogram -> dinv; counting-sort edges by src
// octant IN PLACE (gives the aggregates' L2-window locality). uint4-
// vectorized region load + writeback (4 edges/thread/instr).
// ---------------------------------------------------------------------------
__global__ __launch_bounds__(256) void finalize_csr(
    const int* __restrict__ bcur,
    unsigned int* __restrict__ ebuf,
    float* __restrict__ dinv) {
    __shared__ __align__(16) unsigned int lbuf[CAP];   // 16 KB  raw edges
    __shared__ __align__(16) unsigned int sbuf[CAP];   // 16 KB  sorted edges
    __shared__ int lhist[NPB];
    __shared__ int oh[8];
    __shared__ int obase[8];
    __shared__ int ocur[8];
    int b = blockIdx.x, t = threadIdx.x;
    int n0 = b * NPB;
    int nn = N_NODES - n0; if (nn > NPB) nn = NPB; if (nn < 0) nn = 0;
    int cnt = bcur[b] - b * CAP;
    unsigned int* reg = ebuf + (size_t)b * CAP;

    for (int j = t; j < NPB; j += 256) lhist[j] = 0;
    if (t < 8) oh[t] = 0;
    __syncthreads();

    int c4 = cnt >> 2;                    // full uint4 groups
    const uint4* reg4 = reinterpret_cast<const uint4*>(reg);
    for (int i4 = t; i4 < c4; i4 += 256) {
        uint4 e4 = reg4[i4];
        reinterpret_cast<uint4*>(lbuf)[i4] = e4;
        atomicAdd(&lhist[e4.x & 255u], 1); atomicAdd(&oh[(e4.x >> 8) / OCTN], 1);
        atomicAdd(&lhist[e4.y & 255u], 1); atomicAdd(&oh[(e4.y >> 8) / OCTN], 1);
        atomicAdd(&lhist[e4.z & 255u], 1); atomicAdd(&oh[(e4.z >> 8) / OCTN], 1);
        atomicAdd(&lhist[e4.w & 255u], 1); atomicAdd(&oh[(e4.w >> 8) / OCTN], 1);
    }
    for (int i = c4 * 4 + t; i < cnt; i += 256) {
        unsigned int e = reg[i];
        lbuf[i] = e;
        atomicAdd(&lhist[e & 255u], 1);
        atomicAdd(&oh[(e >> 8) / OCTN], 1);
    }
    __syncthreads();

    for (int j = t; j < nn; j += 256)
        dinv[n0 + j] = rsqrtf((float)(lhist[j] + 1));   // self-loop +1

    if (t == 0) {
        int run = 0;
        for (int p = 0; p < 8; ++p) {
            obase[p] = run; ocur[p] = run; run += oh[p];
        }
    }
    __syncthreads();

    for (int i = t; i < cnt; i += 256) {
        unsigned int e = lbuf[i];
        int p = (int)((e >> 8) / OCTN);
        int pos = atomicAdd(&ocur[p], 1);
        sbuf[pos] = e;
    }
    __syncthreads();

    uint4* reg4w = reinterpret_cast<uint4*>(reg);
    for (int i4 = t; i4 < c4; i4 += 256)
        reg4w[i4] = reinterpret_cast<const uint4*>(sbuf)[i4];
    for (int i = c4 * 4 + t; i < cnt; i += 256)
        reg[i] = sbuf[i];
}

// ---------------------------------------------------------------------------
// GEMM1 via MFMA 16x16x32 bf16 with dual split-bf16 (x=hi+lo, W1=hi+lo,
// 3 products) => f32-level precision. One wave = 16-node x 32-ch tile,
// TPW tiles per wave. h1u[n][ch] = bf16( (x[n]·W1[:,ch]) * dinv[n] ).
// ---------------------------------------------------------------------------
__global__ __launch_bounds__(256) void gemm1_mfma(
    const float* __restrict__ x,
    const float* __restrict__ W1,
    const float* __restrict__ dinv,
    unsigned short* __restrict__ h1u) {
    int wv   = blockIdx.x * 4 + (threadIdx.x >> 6);
    int lane = threadIdx.x & 63;
    int lq   = lane & 15;          // A-row / B-col / C-col index
    int kh   = lane >> 4;          // k-block (8 k's each)

    // --- B fragments from W1[128][32]: hi/lo split, 2 n-tiles x 4 k-steps
    frag_u bh[2][4], bl[2][4];
#pragma unroll
    for (int t = 0; t < 2; ++t) {
#pragma unroll
        for (int s = 0; s < 4; ++s) {
            int ch = t * 16 + lq;
            int k0 = s * 32 + kh * 8;
            float w[8], wh[8];
#pragma unroll
            for (int i = 0; i < 8; ++i) {
                w[i]  = W1[(k0 + i) * HID + ch];
                wh[i] = hif(w[i]);
            }
#pragma unroll
            for (int j = 0; j < 4; ++j) {
                bh[t][s].u[j] = tpack(wh[2 * j], wh[2 * j + 1]);
                bl[t][s].u[j] = tpack(w[2 * j] - wh[2 * j],
                                      w[2 * j + 1] - wh[2 * j + 1]);
            }
        }
    }

#pragma unroll 1
    for (int it = 0; it < TPW; ++it) {
        int tile = wv * TPW + it;
        if (tile >= NTILE) return;
        int n0 = tile * 16;
        const float* xr = x + (size_t)(n0 + lq) * IN_CH;

        f32x4 acc0 = {0.f, 0.f, 0.f, 0.f};
        f32x4 acc1 = {0.f, 0.f, 0.f, 0.f};
#pragma unroll
        for (int s = 0; s < 4; ++s) {
            int k0 = s * 32 + kh * 8;
            float4 v0 = *reinterpret_cast<const float4*>(xr + k0);
            float4 v1 = *reinterpret_cast<const float4*>(xr + k0 + 4);
            frag_u ah, al;
            ah.u[0] = tpack(v0.x, v0.y);
            ah.u[1] = tpack(v0.z, v0.w);
            ah.u[2] = tpack(v1.x, v1.y);
            ah.u[3] = tpack(v1.z, v1.w);
            al.u[0] = tpack(v0.x - hif(v0.x), v0.y - hif(v0.y));
            al.u[1] = tpack(v0.z - hif(v0.z), v0.w - hif(v0.w));
            al.u[2] = tpack(v1.x - hif(v1.x), v1.y - hif(v1.y));
            al.u[3] = tpack(v1.z - hif(v1.z), v1.w - hif(v1.w));

            acc0 = __builtin_amdgcn_mfma_f32_16x16x32_bf16(ah.f, bh[0][s].f, acc0, 0, 0, 0);
            acc0 = __builtin_amdgcn_mfma_f32_16x16x32_bf16(al.f, bh[0][s].f, acc0, 0, 0, 0);
            acc0 = __builtin_amdgcn_mfma_f32_16x16x32_bf16(ah.f, bl[0][s].f, acc0, 0, 0, 0);
            acc1 = __builtin_amdgcn_mfma_f32_16x16x32_bf16(ah.f, bh[1][s].f, acc1, 0, 0, 0);
            acc1 = __builtin_amdgcn_mfma_f32_16x16x32_bf16(al.f, bh[1][s].f, acc1, 0, 0, 0);
            acc1 = __builtin_amdgcn_mfma_f32_16x16x32_bf16(ah.f, bl[1][s].f, acc1, 0, 0, 0);
        }

        // epilogue: C row = kh*4 + j (node), col = lq (channel within tile)
#pragma unroll
        for (int j = 0; j < 4; ++j) {
            int node = n0 + kh * 4 + j;
            float dn = dinv[node];
            unsigned short* dst = h1u + (size_t)node * 32 + lq;
            dst[0]  = bf16_rne(acc0[j] * dn);
            dst[16] = bf16_rne(acc1[j] * dn);
        }
    }
}

// --- bucket-resident aggregation helpers -----------------------------------
__device__ __forceinline__ uint4 row_q(const unsigned int* __restrict__ hb,
                                       unsigned int s, int q4) {
    return *reinterpret_cast<const uint4*>(hb + (size_t)s * 16 + q4);
}

// native ds_add_u32 fire-and-forget: int fixed-point accumulate
__device__ __forceinline__ void fx_scatter8(int* acc, unsigned int e,
                                            int co, uint4 v) {
    int* a = acc + (int)(e & 255u) * ACC_LD + co;
    atomicAdd(&a[0], f2fx(bf_lo(v.x))); atomicAdd(&a[1], f2fx(bf_hi(v.x)));
    atomicAdd(&a[2], f2fx(bf_lo(v.y))); atomicAdd(&a[3], f2fx(bf_hi(v.y)));
    atomicAdd(&a[4], f2fx(bf_lo(v.z))); atomicAdd(&a[5], f2fx(bf_hi(v.z)));
    atomicAdd(&a[6], f2fx(bf_lo(v.w))); atomicAdd(&a[7], f2fx(bf_hi(v.w)));
}

// ---------------------------------------------------------------------------
// Layer-1 aggregate: FLAT walk of the octant-sorted region (sorted order
// preserves the cross-block L2 window), 8-deep unrolled gathers (8 loads
// in flight per lane). Int fixed-point LDS acc. Epilogue: relu+GEMM2
// (h2 in-place), *dinv -> h3b.
// ---------------------------------------------------------------------------
__global__ __launch_bounds__(512, 8) void agg1_flat(
    const int* __restrict__ bcur,
    const unsigned int* __restrict__ ebuf,
    const unsigned int* __restrict__ h1b,
    const float* __restrict__ dinv,
    const float* __restrict__ b1,
    const float* __restrict__ W2,
    unsigned int* __restrict__ h3b) {
    __shared__ int acc[NPB * ACC_LD];        // 12.9 KB
    __shared__ float w2s[HID * HID];         // 4 KB
    __shared__ float b1s[HID];
    int b = blockIdx.x, t = threadIdx.x;
    int n0 = b * NPB;
    int nn = N_NODES - n0; if (nn > NPB) nn = NPB; if (nn < 0) nn = 0;
    int cnt = bcur[b] - b * CAP;
    const unsigned int* reg = ebuf + (size_t)b * CAP;

    for (int i = t; i < HID * HID; i += 512) w2s[i] = W2[i];
    if (t < HID) b1s[t] = b1[t];

    // init acc with self-loop row (h1b already carries dinv[n])
    for (int u = t; u < nn * 4; u += 512) {
        int n = u >> 2, q = u & 3;
        uint4 sv = *reinterpret_cast<const uint4*>(h1b + (size_t)(n0 + n) * 16 + 4 * q);
        int* a = &acc[n * ACC_LD + 8 * q];
        a[0] = f2fx(bf_lo(sv.x)); a[1] = f2fx(bf_hi(sv.x));
        a[2] = f2fx(bf_lo(sv.y)); a[3] = f2fx(bf_hi(sv.y));
        a[4] = f2fx(bf_lo(sv.z)); a[5] = f2fx(bf_hi(sv.z));
        a[6] = f2fx(bf_lo(sv.w)); a[7] = f2fx(bf_hi(sv.w));
    }
    __syncthreads();

    int q4 = (t & 3) * 4;      // u32 offset of this lane's quarter-row
    int co = (t & 3) * 8;      // channel offset
    int i  = t >> 2;           // quad id in [0,128)
    for (; i + 896 < cnt; i += 1024) {       // 8 gathers in flight
        unsigned int e0 = reg[i];
        unsigned int e1 = reg[i + 128];
        unsigned int e2 = reg[i + 256];
        unsigned int e3 = reg[i + 384];
        unsigned int e4 = reg[i + 512];
        unsigned int e5 = reg[i + 640];
        unsigned int e6 = reg[i + 768];
        unsigned int e7 = reg[i + 896];
        uint4 v0 = row_q(h1b, e0 >> 8, q4);
        uint4 v1 = row_q(h1b, e1 >> 8, q4);
        uint4 v2 = row_q(h1b, e2 >> 8, q4);
        uint4 v3 = row_q(h1b, e3 >> 8, q4);
        uint4 v4 = row_q(h1b, e4 >> 8, q4);
        uint4 v5 = row_q(h1b, e5 >> 8, q4);
        uint4 v6 = row_q(h1b, e6 >> 8, q4);
        uint4 v7 = row_q(h1b, e7 >> 8, q4);
        fx_scatter8(acc, e0, co, v0);
        fx_scatter8(acc, e1, co, v1);
        fx_scatter8(acc, e2, co, v2);
        fx_scatter8(acc, e3, co, v3);
        fx_scatter8(acc, e4, co, v4);
        fx_scatter8(acc, e5, co, v5);
        fx_scatter8(acc, e6, co, v6);
        fx_scatter8(acc, e7, co, v7);
    }
    for (; i + 384 < cnt; i += 512) {        // 4 gathers in flight
        unsigned int e0 = reg[i];
        unsigned int e1 = reg[i + 128];
        unsigned int e2 = reg[i + 256];
        unsigned int e3 = reg[i + 384];
        uint4 v0 = row_q(h1b, e0 >> 8, q4);
        uint4 v1 = row_q(h1b, e1 >> 8, q4);
        uint4 v2 = row_q(h1b, e2 >> 8, q4);
        uint4 v3 = row_q(h1b, e3 >> 8, q4);
        fx_scatter8(acc, e0, co, v0);
        fx_scatter8(acc, e1, co, v1);
        fx_scatter8(acc, e2, co, v2);
        fx_scatter8(acc, e3, co, v3);
    }
    for (; i < cnt; i += 128) {
        unsigned int e = reg[i];
        uint4 v = row_q(h1b, e >> 8, q4);
        fx_scatter8(acc, e, co, v);
    }
    __syncthreads();

    // h2 = relu(acc * dinv + b1), converted IN PLACE (same slot, same thread)
    float* h2s = (float*)acc;
    for (int u = t; u < nn * HID; u += 512) {
        int n = u >> 5, j = u & 31;
        float v = (float)acc[n * ACC_LD + j] * FXI * dinv[n0 + n] + b1s[j];
        h2s[n * ACC_LD + j] = v > 0.f ? v : 0.f;
    }
    __syncthreads();

    // GEMM2: 4 threads per node, 8 output channels each -> h3b (bf16x2)
    for (int u = t; u < nn * 4; u += 512) {
        int n = u >> 2, qq = u & 3;
        const float* h2 = &h2s[n * ACC_LD];
        float a2[8];
#pragma unroll
        for (int k = 0; k < 8; ++k) a2[k] = 0.f;
#pragma unroll
        for (int j = 0; j < HID; ++j) {
            float hj = h2[j];
            const float* wr = &w2s[j * HID + 8 * qq];
#pragma unroll
            for (int k = 0; k < 8; ++k) a2[k] += hj * wr[k];
        }
        float dn = dinv[n0 + n];
        unsigned int* dst = h3b + (size_t)(n0 + n) * 16 + 4 * qq;
        *reinterpret_cast<uint4*>(dst) = make_uint4(
            pack_bf16x2(a2[0] * dn, a2[1] * dn),
            pack_bf16x2(a2[2] * dn, a2[3] * dn),
            pack_bf16x2(a2[4] * dn, a2[5] * dn),
            pack_bf16x2(a2[6] * dn, a2[7] * dn));
    }
}

// ---------------------------------------------------------------------------
// Layer-2 aggregate: same flat 8-deep structure; epilogue2 -> f32 out.
// ---------------------------------------------------------------------------
__global__ __launch_bounds__(512, 8) void agg2_flat(
    const int* __restrict__ bcur,
    const unsigned int* __restrict__ ebuf,
    const unsigned int* __restrict__ h3b,
    const float* __restrict__ dinv,
    const float* __restrict__ b2,
    float* __restrict__ out) {
    __shared__ int acc[NPB * ACC_LD];        // 12.9 KB
    __shared__ float b2s[HID];
    int b = blockIdx.x, t = threadIdx.x;
    int n0 = b * NPB;
    int nn = N_NODES - n0; if (nn > NPB) nn = NPB; if (nn < 0) nn = 0;
    int cnt = bcur[b] - b * CAP;
    const unsigned int* reg = ebuf + (size_t)b * CAP;

    if (t < HID) b2s[t] = b2[t];

    for (int u = t; u < nn * 4; u += 512) {
        int n = u >> 2, q = u & 3;
        uint4 sv = *reinterpret_cast<const uint4*>(h3b + (size_t)(n0 + n) * 16 + 4 * q);
        int* a = &acc[n * ACC_LD + 8 * q];
        a[0] = f2fx(bf_lo(sv.x)); a[1] = f2fx(bf_hi(sv.x));
        a[2] = f2fx(bf_lo(sv.y)); a[3] = f2fx(bf_hi(sv.y));
        a[4] = f2fx(bf_lo(sv.z)); a[5] = f2fx(bf_hi(sv.z));
        a[6] = f2fx(bf_lo(sv.w)); a[7] = f2fx(bf_hi(sv.w));
    }
    __syncthreads();

    int q4 = (t & 3) * 4;
    int co = (t & 3) * 8;
    int i  = t >> 2;
    for (; i + 896 < cnt; i += 1024) {
        unsigned int e0 = reg[i];
        unsigned int e1 = reg[i + 128];
        unsigned int e2 = reg[i + 256];
        unsigned int e3 = reg[i + 384];
        unsigned int e4 = reg[i + 512];
        unsigned int e5 = reg[i + 640];
        unsigned int e6 = reg[i + 768];
        unsigned int e7 = reg[i + 896];
        uint4 v0 = row_q(h3b, e0 >> 8, q4);
        uint4 v1 = row_q(h3b, e1 >> 8, q4);
        uint4 v2 = row_q(h3b, e2 >> 8, q4);
        uint4 v3 = row_q(h3b, e3 >> 8, q4);
        uint4 v4 = row_q(h3b, e4 >> 8, q4);
        uint4 v5 = row_q(h3b, e5 >> 8, q4);
        uint4 v6 = row_q(h3b, e6 >> 8, q4);
        uint4 v7 = row_q(h3b, e7 >> 8, q4);
        fx_scatter8(acc, e0, co, v0);
        fx_scatter8(acc, e1, co, v1);
        fx_scatter8(acc, e2, co, v2);
        fx_scatter8(acc, e3, co, v3);
        fx_scatter8(acc, e4, co, v4);
        fx_scatter8(acc, e5, co, v5);
        fx_scatter8(acc, e6, co, v6);
        fx_scatter8(acc, e7, co, v7);
    }
    for (; i + 384 < cnt; i += 512) {
        unsigned int e0 = reg[i];
        unsigned int e1 = reg[i + 128];
        unsigned int e2 = reg[i + 256];
        unsigned int e3 = reg[i + 384];
        uint4 v0 = row_q(h3b, e0 >> 8, q4);
        uint4 v1 = row_q(h3b, e1 >> 8, q4);
        uint4 v2 = row_q(h3b, e2 >> 8, q4);
        uint4 v3 = row_q(h3b, e3 >> 8, q4);
        fx_scatter8(acc, e0, co, v0);
        fx_scatter8(acc, e1, co, v1);
        fx_scatter8(acc, e2, co, v2);
        fx_scatter8(acc, e3, co, v3);
    }
    for (; i < cnt; i += 128) {
        unsigned int e = reg[i];
        uint4 v = row_q(h3b, e >> 8, q4);
        fx_scatter8(acc, e, co, v);
    }
    __syncthreads();

    // epilogue: 4 threads per node, 8 channels each -> f32 out
    for (int u = t; u < nn * 4; u += 512) {
        int n = u >> 2, qq = u & 3;
        float dn = dinv[n0 + n];
        const int* a = &acc[n * ACC_LD + 8 * qq];
        const float* bb = &b2s[8 * qq];
        float4 o1v, o2v;
        o1v.x = (float)a[0] * FXI * dn + bb[0];
        o1v.y = (float)a[1] * FXI * dn + bb[1];
        o1v.z = (float)a[2] * FXI * dn + bb[2];
        o1v.w = (float)a[3] * FXI * dn + bb[3];
        o2v.x = (float)a[4] * FXI * dn + bb[4];
        o2v.y = (float)a[5] * FXI * dn + bb[5];
        o2v.z = (float)a[6] * FXI * dn + bb[6];
        o2v.w = (float)a[7] * FXI * dn + bb[7];
        float* op = out + (size_t)(n0 + n) * 32 + 8 * qq;
        *reinterpret_cast<float4*>(op)     = o1v;
        *reinterpret_cast<float4*>(op + 4) = o2v;
    }
}

// ---------------------------------------------------------------------------
extern "C" void kernel_launch(void* const* d_in, const int* in_sizes, int n_in,
                              void* d_out, int out_size, void* d_ws, size_t ws_size,
                              hipStream_t stream) {
    const float* x  = (const float*)d_in[0];
    const int*   ei = (const int*)d_in[1];
    const float* W1 = (const float*)d_in[2];
    const float* b1 = (const float*)d_in[3];
    const float* W2 = (const float*)d_in[4];
    const float* b2 = (const float*)d_in[5];
    float* out = (float*)d_out;

    // workspace: flag[64] | bcur[NB] | dinv[N] | ebuf[NB*CAP u32 = 16 MiB] |
    //            h1b (6.4 MB) | h3b (6.4 MB).  Total ~29.4 MiB.
    int*          flag = (int*)d_ws;
    int*          bcur = flag + 64;
    float*        dinv = (float*)(bcur + NB);
    unsigned int* ebuf = (unsigned int*)(dinv + N_NODES);
    unsigned int* h1b  = ebuf + (size_t)NB * CAP;
    unsigned int* h3b  = h1b + (size_t)N_NODES * 16;

    const int chunkBlocks = (N_EDGES + CHUNK - 1) / CHUNK;      // 391
    const int g1Blocks    = (NTILE + 4 * TPW - 1) / (4 * TPW);  // 782

    detect_init<<<1, 256, 0, stream>>>(ei, flag, bcur);

    // bucketed edge partition (reg-staged, stagger-reserved, sorted flush)
    scatter7<<<chunkBlocks, 512, 0, stream>>>(ei, flag, bcur, ebuf);
    finalize_csr<<<NB, 256, 0, stream>>>(bcur, ebuf, dinv);

    // layer 1 (+ fused relu + gemm2)
    gemm1_mfma<<<g1Blocks, 256, 0, stream>>>(x, W1, dinv,
                                             (unsigned short*)h1b);
    agg1_flat<<<NB, 512, 0, stream>>>(bcur, ebuf, h1b, dinv, b1, W2, h3b);

    // layer 2 (+ fused epilogue)
    agg2_flat<<<NB, 512, 0, stream>>>(bcur, ebuf, h3b, dinv, b2, out);
}

// Round 13
// 201.523 us; speedup vs baseline: 1.0458x; 1.0458x over previous
//
#include <hip/hip_runtime.h>
#include <hip/hip_bf16.h>

#define N_NODES 100000
#define N_EDGES 3200000
#define IN_CH   128
#define HID     32
#define NB      1024             // dst buckets
#define NPB     98               // nodes per bucket (1024*98 = 100352 >= 100000)
#define CAP     4096             // per-bucket capacity (mean 3125, sigma 56, +17 sigma)
#define CHUNK   8192             // edges per block in scatter7
#define EPT     16               // edges per thread (CHUNK/512)
#define ACC_LD  33               // padded acc row stride
#define OCTN    12500u           // nodes per octant (finalize sort key)
#define FXS     1048576.0f       // 2^20 fixed-point scale
#define FXI     (1.0f/1048576.0f)
#define NTILE   6250             // 16-node MFMA tiles (100000/16 exact)
#define TPW     2                // tiles per wave in gemm1

// --- bf16 helpers ----------------------------------------------------------
__device__ __forceinline__ unsigned int pack_bf16x2(float a, float b) {
    unsigned int ua = __float_as_uint(a);
    unsigned int ub = __float_as_uint(b);
    ua = (ua + 0x7FFFu + ((ua >> 16) & 1u)) >> 16;
    ub = (ub + 0x7FFFu + ((ub >> 16) & 1u)) >> 16;
    return (ua & 0xFFFFu) | (ub << 16);
}
__device__ __forceinline__ float bf_lo(unsigned int v) { return __uint_as_float(v << 16); }
__device__ __forceinline__ float bf_hi(unsigned int v) { return __uint_as_float(v & 0xFFFF0000u); }
__device__ __forceinline__ int   f2fx(float f)         { return (int)(f * FXS); }
// truncate-to-bf16 as float (zero low mantissa bits)
__device__ __forceinline__ float hif(float f) {
    return __uint_as_float(__float_as_uint(f) & 0xFFFF0000u);
}
// pack two floats' TOP 16 bits (truncation) into one u32 (lo=a, hi=b)
__device__ __forceinline__ unsigned int tpack(float a, float b) {
    return (__float_as_uint(a) >> 16) | (__float_as_uint(b) & 0xFFFF0000u);
}
__device__ __forceinline__ unsigned short bf16_rne(float f) {
    unsigned int u = __float_as_uint(f);
    return (unsigned short)((u + 0x7FFFu + ((u >> 16) & 1u)) >> 16);
}

typedef short bf16x8 __attribute__((ext_vector_type(8)));
typedef float f32x4  __attribute__((ext_vector_type(4)));
union frag_u { bf16x8 f; unsigned int u[4]; };

// ---------------------------------------------------------------------------
// Detect int64 vs int32 edge_index; init bcur cursors. One block.
// ---------------------------------------------------------------------------
__global__ __launch_bounds__(256) void detect_init(const int* __restrict__ ei,
                                                   int* __restrict__ flag,
                                                   int* __restrict__ bcur) {
    __shared__ int nz;
    for (int j = threadIdx.x; j < NB; j += 256) bcur[j] = j * CAP;
    if (threadIdx.x == 0) nz = 0;
    __syncthreads();
    if (ei[2 * threadIdx.x + 1] != 0) atomicAdd(&nz, 1);
    __syncthreads();
    if (threadIdx.x == 0) flag[0] = (nz == 0) ? 1 : 0;
}

__device__ __forceinline__ int edge_at(const int* __restrict__ ei, int idx64,
                                       size_t pos) {
    if (idx64) return (int)((const long long*)ei)[pos];
    return ei[pos];
}

// ---------------------------------------------------------------------------
// Scatter edges into fixed-capacity dst-bucket regions of ebuf, 4 B packed
// (s<<8)|dloc. Register-staged single global read; LDS bucket sort; LINEAR
// flush (contiguous per-bucket runs, wave-coalesced). Reservation loop is
// ROTATED per block to decorrelate global-atomic bursts. 1024-bin offset
// scan done with wave shuffles (2 barriers instead of 20).
// ---------------------------------------------------------------------------
__global__ __launch_bounds__(512) void scatter7(
    const int* __restrict__ ei,
    const int* __restrict__ flag,
    int* __restrict__ bcur,
    unsigned int* __restrict__ ebuf) {
    __shared__ int cnt[NB];               // 4 KB  histogram, then cursor
    __shared__ int loff[NB];              // 4 KB  local exclusive offsets
    __shared__ int dlt[NB];               // 4 KB  global_base - loff
    __shared__ int wsum[8];               // wave totals for the scan
    __shared__ unsigned int   sbuf[CHUNK];// 32 KB sorted edges
    __shared__ unsigned short sbb[CHUNK]; // 16 KB bucket id per sorted slot

    int t = threadIdx.x;
    for (int j = t; j < NB; j += 512) cnt[j] = 0;
    __syncthreads();

    int e0 = blockIdx.x * CHUNK;
    int nE = N_EDGES - e0; if (nE > CHUNK) nE = CHUNK;
    int idx64 = flag[0];

    // single global read: stage this thread's <=16 edges in registers
    unsigned int rs[EPT], rd[EPT];
#pragma unroll
    for (int j = 0; j < EPT; ++j) {
        int i = t + j * 512;
        if (i < nE) {
            rs[j] = (unsigned int)edge_at(ei, idx64, (size_t)(e0 + i));
            rd[j] = (unsigned int)edge_at(ei, idx64, (size_t)N_EDGES + e0 + i);
        }
    }

    // dst histogram from registers (LDS atomics, native int)
#pragma unroll
    for (int j = 0; j < EPT; ++j) {
        int i = t + j * 512;
        if (i < nE) atomicAdd(&cnt[rd[j] / NPB], 1);
    }
    __syncthreads();

    // exclusive scan of cnt[1024]: thread t owns bins 2t, 2t+1.
    // Wave-shuffle inclusive scan of per-thread sums, then 8-wave combine.
    int c0 = cnt[2 * t], c1 = cnt[2 * t + 1];
    int s = c0 + c1;
    int lane = t & 63, wid = t >> 6;
    int sc = s;
#pragma unroll
    for (int off = 1; off < 64; off <<= 1) {
        int x = __shfl_up(sc, off, 64);
        if (lane >= off) sc += x;
    }
    if (lane == 63) wsum[wid] = sc;       // wave total
    __syncthreads();
    if (t == 0) {
        int run = 0;
#pragma unroll
        for (int w = 0; w < 8; ++w) { int v = wsum[w]; wsum[w] = run; run += v; }
    }
    __syncthreads();
    int base = wsum[wid] + sc - s;        // exclusive prefix for this thread
    loff[2 * t]     = base;
    loff[2 * t + 1] = base + c0;
    __syncthreads();

    // staggered reservation: rotate per block to decorrelate atomic bursts
    int rot = (blockIdx.x * 211) & (NB - 1);
    for (int jj = t; jj < NB; jj += 512) {
        int j = (jj + rot) & (NB - 1);
        int c = cnt[j];
        int gb = (c > 0) ? atomicAdd(&bcur[j], c) : 0;
        dlt[j] = gb - loff[j];
        cnt[j] = 0;                       // reuse as scatter cursor
    }
    __syncthreads();

    // LDS bucket-sort from registers
#pragma unroll
    for (int j = 0; j < EPT; ++j) {
        int i = t + j * 512;
        if (i < nE) {
            unsigned int b = rd[j] / NPB; // compile-time const -> magic mul
            int pos = loff[b] + atomicAdd(&cnt[b], 1);
            sbuf[pos] = (rs[j] << 8) | (rd[j] - b * NPB);
            sbb[pos]  = (unsigned short)b;
        }
    }
    __syncthreads();

    // linear flush -> contiguous per-bucket runs, wave-coalesced
    for (int i = t; i < nE; i += 512)
        ebuf[dlt[sbb[i]] + i] = sbuf[i];
}

// ---------------------------------------------------------------------------
// Per-bucket finalize: dst histogram -> dinv; counting-sort edges by src
// octant IN PLACE (gives the aggregates' L2-window locality).
// ---------------------------------------------------------------------------
__global__ __launch_bounds__(256) void finalize_csr(
    const int* __restrict__ bcur,
    unsigned int* __restrict__ ebuf,
    float* __restrict__ dinv) {
    __shared__ unsigned int lbuf[CAP];   // 16 KB  raw edges
    __shared__ unsigned int sbuf[CAP];   // 16 KB  octant-sorted edges
    __shared__ int lhist[NPB];
    __shared__ int oh[8];
    __shared__ int obase[8];
    __shared__ int ocur[8];
    int b = blockIdx.x, t = threadIdx.x;
    int n0 = b * NPB;
    int nn = N_NODES - n0; if (nn > NPB) nn = NPB; if (nn < 0) nn = 0;
    int cnt = bcur[b] - b * CAP;
    unsigned int* reg = ebuf + (size_t)b * CAP;

    for (int j = t; j < NPB; j += 256) lhist[j] = 0;
    if (t < 8) oh[t] = 0;
    __syncthreads();

    for (int i = t; i < cnt; i += 256) {
        unsigned int e = reg[i];
        lbuf[i] = e;
        atomicAdd(&lhist[e & 255u], 1);
        atomicAdd(&oh[(e >> 8) / OCTN], 1);
    }
    __syncthreads();

    for (int j = t; j < nn; j += 256)
        dinv[n0 + j] = rsqrtf((float)(lhist[j] + 1));   // self-loop +1

    if (t == 0) {
        int run = 0;
        for (int p = 0; p < 8; ++p) {
            obase[p] = run; ocur[p] = run; run += oh[p];
        }
    }
    __syncthreads();

    for (int i = t; i < cnt; i += 256) {
        unsigned int e = lbuf[i];
        int p = (int)((e >> 8) / OCTN);
        int pos = atomicAdd(&ocur[p], 1);
        sbuf[pos] = e;
    }
    __syncthreads();

    for (int i = t; i < cnt; i += 256)
        reg[i] = sbuf[i];
}

// ---------------------------------------------------------------------------
// GEMM1 via MFMA 16x16x32 bf16 with dual split-bf16 (x=hi+lo, W1=hi+lo,
// 3 products) => f32-level precision. One wave = 16-node x 32-ch tile,
// TPW tiles per wave. h1u[n][ch] = bf16( (x[n]·W1[:,ch]) * dinv[n] ).
// ---------------------------------------------------------------------------
__global__ __launch_bounds__(256) void gemm1_mfma(
    const float* __restrict__ x,
    const float* __restrict__ W1,
    const float* __restrict__ dinv,
    unsigned short* __restrict__ h1u) {
    int wv   = blockIdx.x * 4 + (threadIdx.x >> 6);
    int lane = threadIdx.x & 63;
    int lq   = lane & 15;          // A-row / B-col / C-col index
    int kh   = lane >> 4;          // k-block (8 k's each)

    // --- B fragments from W1[128][32]: hi/lo split, 2 n-tiles x 4 k-steps
    frag_u bh[2][4], bl[2][4];
#pragma unroll
    for (int t = 0; t < 2; ++t) {
#pragma unroll
        for (int s = 0; s < 4; ++s) {
            int ch = t * 16 + lq;
            int k0 = s * 32 + kh * 8;
            float w[8], wh[8];
#pragma unroll
            for (int i = 0; i < 8; ++i) {
                w[i]  = W1[(k0 + i) * HID + ch];
                wh[i] = hif(w[i]);
            }
#pragma unroll
            for (int j = 0; j < 4; ++j) {
                bh[t][s].u[j] = tpack(wh[2 * j], wh[2 * j + 1]);
                bl[t][s].u[j] = tpack(w[2 * j] - wh[2 * j],
                                      w[2 * j + 1] - wh[2 * j + 1]);
            }
        }
    }

#pragma unroll 1
    for (int it = 0; it < TPW; ++it) {
        int tile = wv * TPW + it;
        if (tile >= NTILE) return;
        int n0 = tile * 16;
        const float* xr = x + (size_t)(n0 + lq) * IN_CH;

        f32x4 acc0 = {0.f, 0.f, 0.f, 0.f};
        f32x4 acc1 = {0.f, 0.f, 0.f, 0.f};
#pragma unroll
        for (int s = 0; s < 4; ++s) {
            int k0 = s * 32 + kh * 8;
            float4 v0 = *reinterpret_cast<const float4*>(xr + k0);
            float4 v1 = *reinterpret_cast<const float4*>(xr + k0 + 4);
            frag_u ah, al;
            ah.u[0] = tpack(v0.x, v0.y);
            ah.u[1] = tpack(v0.z, v0.w);
            ah.u[2] = tpack(v1.x, v1.y);
            ah.u[3] = tpack(v1.z, v1.w);
            al.u[0] = tpack(v0.x - hif(v0.x), v0.y - hif(v0.y));
            al.u[1] = tpack(v0.z - hif(v0.z), v0.w - hif(v0.w));
            al.u[2] = tpack(v1.x - hif(v1.x), v1.y - hif(v1.y));
            al.u[3] = tpack(v1.z - hif(v1.z), v1.w - hif(v1.w));

            acc0 = __builtin_amdgcn_mfma_f32_16x16x32_bf16(ah.f, bh[0][s].f, acc0, 0, 0, 0);
            acc0 = __builtin_amdgcn_mfma_f32_16x16x32_bf16(al.f, bh[0][s].f, acc0, 0, 0, 0);
            acc0 = __builtin_amdgcn_mfma_f32_16x16x32_bf16(ah.f, bl[0][s].f, acc0, 0, 0, 0);
            acc1 = __builtin_amdgcn_mfma_f32_16x16x32_bf16(ah.f, bh[1][s].f, acc1, 0, 0, 0);
            acc1 = __builtin_amdgcn_mfma_f32_16x16x32_bf16(al.f, bh[1][s].f, acc1, 0, 0, 0);
            acc1 = __builtin_amdgcn_mfma_f32_16x16x32_bf16(ah.f, bl[1][s].f, acc1, 0, 0, 0);
        }

        // epilogue: C row = kh*4 + j (node), col = lq (channel within tile)
#pragma unroll
        for (int j = 0; j < 4; ++j) {
            int node = n0 + kh * 4 + j;
            float dn = dinv[node];
            unsigned short* dst = h1u + (size_t)node * 32 + lq;
            dst[0]  = bf16_rne(acc0[j] * dn);
            dst[16] = bf16_rne(acc1[j] * dn);
        }
    }
}

// --- bucket-resident aggregation helpers -----------------------------------
__device__ __forceinline__ uint4 row_q(const unsigned int* __restrict__ hb,
                                       unsigned int s, int q4) {
    return *reinterpret_cast<const uint4*>(hb + (size_t)s * 16 + q4);
}

// native ds_add_u32 fire-and-forget: int fixed-point accumulate
__device__ __forceinline__ void fx_scatter8(int* acc, unsigned int e,
                                            int co, uint4 v) {
    int* a = acc + (int)(e & 255u) * ACC_LD + co;
    atomicAdd(&a[0], f2fx(bf_lo(v.x))); atomicAdd(&a[1], f2fx(bf_hi(v.x)));
    atomicAdd(&a[2], f2fx(bf_lo(v.y))); atomicAdd(&a[3], f2fx(bf_hi(v.y)));
    atomicAdd(&a[4], f2fx(bf_lo(v.z))); atomicAdd(&a[5], f2fx(bf_hi(v.z)));
    atomicAdd(&a[6], f2fx(bf_lo(v.w))); atomicAdd(&a[7], f2fx(bf_hi(v.w)));
}

// ---------------------------------------------------------------------------
// Layer-1 aggregate: FLAT walk of the octant-sorted region (sorted order
// preserves the cross-block L2 window), 4-deep unrolled gathers. Int
// fixed-point LDS acc. Epilogue: relu+GEMM2 (h2 in-place), *dinv -> h3b.
// ---------------------------------------------------------------------------
__global__ __launch_bounds__(512, 8) void agg1_flat(
    const int* __restrict__ bcur,
    const unsigned int* __restrict__ ebuf,
    const unsigned int* __restrict__ h1b,
    const float* __restrict__ dinv,
    const float* __restrict__ b1,
    const float* __restrict__ W2,
    unsigned int* __restrict__ h3b) {
    __shared__ int acc[NPB * ACC_LD];        // 12.9 KB
    __shared__ float w2s[HID * HID];         // 4 KB
    __shared__ float b1s[HID];
    int b = blockIdx.x, t = threadIdx.x;
    int n0 = b * NPB;
    int nn = N_NODES - n0; if (nn > NPB) nn = NPB; if (nn < 0) nn = 0;
    int cnt = bcur[b] - b * CAP;
    const unsigned int* reg = ebuf + (size_t)b * CAP;

    for (int i = t; i < HID * HID; i += 512) w2s[i] = W2[i];
    if (t < HID) b1s[t] = b1[t];

    // init acc with self-loop row (h1b already carries dinv[n])
    for (int u = t; u < nn * 4; u += 512) {
        int n = u >> 2, q = u & 3;
        uint4 sv = *reinterpret_cast<const uint4*>(h1b + (size_t)(n0 + n) * 16 + 4 * q);
        int* a = &acc[n * ACC_LD + 8 * q];
        a[0] = f2fx(bf_lo(sv.x)); a[1] = f2fx(bf_hi(sv.x));
        a[2] = f2fx(bf_lo(sv.y)); a[3] = f2fx(bf_hi(sv.y));
        a[4] = f2fx(bf_lo(sv.z)); a[5] = f2fx(bf_hi(sv.z));
        a[6] = f2fx(bf_lo(sv.w)); a[7] = f2fx(bf_hi(sv.w));
    }
    __syncthreads();

    int q4 = (t & 3) * 4;      // u32 offset of this lane's quarter-row
    int co = (t & 3) * 8;      // channel offset
    int i  = t >> 2;           // quad id in [0,128)
    for (; i + 384 < cnt; i += 512) {        // 4 gathers in flight
        unsigned int e0 = reg[i];
        unsigned int e1 = reg[i + 128];
        unsigned int e2 = reg[i + 256];
        unsigned int e3 = reg[i + 384];
        uint4 v0 = row_q(h1b, e0 >> 8, q4);
        uint4 v1 = row_q(h1b, e1 >> 8, q4);
        uint4 v2 = row_q(h1b, e2 >> 8, q4);
        uint4 v3 = row_q(h1b, e3 >> 8, q4);
        fx_scatter8(acc, e0, co, v0);
        fx_scatter8(acc, e1, co, v1);
        fx_scatter8(acc, e2, co, v2);
        fx_scatter8(acc, e3, co, v3);
    }
    for (; i < cnt; i += 128) {
        unsigned int e = reg[i];
        uint4 v = row_q(h1b, e >> 8, q4);
        fx_scatter8(acc, e, co, v);
    }
    __syncthreads();

    // h2 = relu(acc * dinv + b1), converted IN PLACE (same slot, same thread)
    float* h2s = (float*)acc;
    for (int u = t; u < nn * HID; u += 512) {
        int n = u >> 5, j = u & 31;
        float v = (float)acc[n * ACC_LD + j] * FXI * dinv[n0 + n] + b1s[j];
        h2s[n * ACC_LD + j] = v > 0.f ? v : 0.f;
    }
    __syncthreads();

    // GEMM2: 4 threads per node, 8 output channels each -> h3b (bf16x2)
    for (int u = t; u < nn * 4; u += 512) {
        int n = u >> 2, qq = u & 3;
        const float* h2 = &h2s[n * ACC_LD];
        float a2[8];
#pragma unroll
        for (int k = 0; k < 8; ++k) a2[k] = 0.f;
#pragma unroll
        for (int j = 0; j < HID; ++j) {
            float hj = h2[j];
            const float* wr = &w2s[j * HID + 8 * qq];
#pragma unroll
            for (int k = 0; k < 8; ++k) a2[k] += hj * wr[k];
        }
        float dn = dinv[n0 + n];
        unsigned int* dst = h3b + (size_t)(n0 + n) * 16 + 4 * qq;
        *reinterpret_cast<uint4*>(dst) = make_uint4(
            pack_bf16x2(a2[0] * dn, a2[1] * dn),
            pack_bf16x2(a2[2] * dn, a2[3] * dn),
            pack_bf16x2(a2[4] * dn, a2[5] * dn),
            pack_bf16x2(a2[6] * dn, a2[7] * dn));
    }
}

// ---------------------------------------------------------------------------
// Layer-2 aggregate: same flat structure; epilogue2 -> f32 out.
// ---------------------------------------------------------------------------
__global__ __launch_bounds__(512, 8) void agg2_flat(
    const int* __restrict__ bcur,
    const unsigned int* __restrict__ ebuf,
    const unsigned int* __restrict__ h3b,
    const float* __restrict__ dinv,
    const float* __restrict__ b2,
    float* __restrict__ out) {
    __shared__ int acc[NPB * ACC_LD];        // 12.9 KB
    __shared__ float b2s[HID];
    int b = blockIdx.x, t = threadIdx.x;
    int n0 = b * NPB;
    int nn = N_NODES - n0; if (nn > NPB) nn = NPB; if (nn < 0) nn = 0;
    int cnt = bcur[b] - b * CAP;
    const unsigned int* reg = ebuf + (size_t)b * CAP;

    if (t < HID) b2s[t] = b2[t];

    for (int u = t; u < nn * 4; u += 512) {
        int n = u >> 2, q = u & 3;
        uint4 sv = *reinterpret_cast<const uint4*>(h3b + (size_t)(n0 + n) * 16 + 4 * q);
        int* a = &acc[n * ACC_LD + 8 * q];
        a[0] = f2fx(bf_lo(sv.x)); a[1] = f2fx(bf_hi(sv.x));
        a[2] = f2fx(bf_lo(sv.y)); a[3] = f2fx(bf_hi(sv.y));
        a[4] = f2fx(bf_lo(sv.z)); a[5] = f2fx(bf_hi(sv.z));
        a[6] = f2fx(bf_lo(sv.w)); a[7] = f2fx(bf_hi(sv.w));
    }
    __syncthreads();

    int q4 = (t & 3) * 4;
    int co = (t & 3) * 8;
    int i  = t >> 2;
    for (; i + 384 < cnt; i += 512) {
        unsigned int e0 = reg[i];
        unsigned int e1 = reg[i + 128];
        unsigned int e2 = reg[i + 256];
        unsigned int e3 = reg[i + 384];
        uint4 v0 = row_q(h3b, e0 >> 8, q4);
        uint4 v1 = row_q(h3b, e1 >> 8, q4);
        uint4 v2 = row_q(h3b, e2 >> 8, q4);
        uint4 v3 = row_q(h3b, e3 >> 8, q4);
        fx_scatter8(acc, e0, co, v0);
        fx_scatter8(acc, e1, co, v1);
        fx_scatter8(acc, e2, co, v2);
        fx_scatter8(acc, e3, co, v3);
    }
    for (; i < cnt; i += 128) {
        unsigned int e = reg[i];
        uint4 v = row_q(h3b, e >> 8, q4);
        fx_scatter8(acc, e, co, v);
    }
    __syncthreads();

    // epilogue: 4 threads per node, 8 channels each -> f32 out
    for (int u = t; u < nn * 4; u += 512) {
        int n = u >> 2, qq = u & 3;
        float dn = dinv[n0 + n];
        const int* a = &acc[n * ACC_LD + 8 * qq];
        const float* bb = &b2s[8 * qq];
        float4 o1v, o2v;
        o1v.x = (float)a[0] * FXI * dn + bb[0];
        o1v.y = (float)a[1] * FXI * dn + bb[1];
        o1v.z = (float)a[2] * FXI * dn + bb[2];
        o1v.w = (float)a[3] * FXI * dn + bb[3];
        o2v.x = (float)a[4] * FXI * dn + bb[4];
        o2v.y = (float)a[5] * FXI * dn + bb[5];
        o2v.z = (float)a[6] * FXI * dn + bb[6];
        o2v.w = (float)a[7] * FXI * dn + bb[7];
        float* op = out + (size_t)(n0 + n) * 32 + 8 * qq;
        *reinterpret_cast<float4*>(op)     = o1v;
        *reinterpret_cast<float4*>(op + 4) = o2v;
    }
}

// ---------------------------------------------------------------------------
extern "C" void kernel_launch(void* const* d_in, const int* in_sizes, int n_in,
                              void* d_out, int out_size, void* d_ws, size_t ws_size,
                              hipStream_t stream) {
    const float* x  = (const float*)d_in[0];
    const int*   ei = (const int*)d_in[1];
    const float* W1 = (const float*)d_in[2];
    const float* b1 = (const float*)d_in[3];
    const float* W2 = (const float*)d_in[4];
    const float* b2 = (const float*)d_in[5];
    float* out = (float*)d_out;

    // workspace: flag[64] | bcur[NB] | dinv[N] | ebuf[NB*CAP u32 = 16 MiB] |
    //            h1b (6.4 MB) | h3b (6.4 MB).  Total ~29.4 MiB.
    int*          flag = (int*)d_ws;
    int*          bcur = flag + 64;
    float*        dinv = (float*)(bcur + NB);
    unsigned int* ebuf = (unsigned int*)(dinv + N_NODES);
    unsigned int* h1b  = ebuf + (size_t)NB * CAP;
    unsigned int* h3b  = h1b + (size_t)N_NODES * 16;

    const int chunkBlocks = (N_EDGES + CHUNK - 1) / CHUNK;      // 391
    const int g1Blocks    = (NTILE + 4 * TPW - 1) / (4 * TPW);  // 782

    detect_init<<<1, 256, 0, stream>>>(ei, flag, bcur);

    // bucketed edge partition (reg-staged, stagger-reserved, sorted flush)
    scatter7<<<chunkBlocks, 512, 0, stream>>>(ei, flag, bcur, ebuf);
    finalize_csr<<<NB, 256, 0, stream>>>(bcur, ebuf, dinv);

    // layer 1 (+ fused relu + gemm2)
    gemm1_mfma<<<g1Blocks, 256, 0, stream>>>(x, W1, dinv,
                                             (unsigned short*)h1b);
    agg1_flat<<<NB, 512, 0, stream>>>(bcur, ebuf, h1b, dinv, b1, W2, h3b);

    // layer 2 (+ fused epilogue)
    agg2_flat<<<NB, 512, 0, stream>>>(bcur, ebuf, h3b, dinv, b2, out);
}